// Round 11
// baseline (81.096 us; speedup 1.0000x reference)
//
#include <hip/hip_runtime.h>
#include <math.h>

// ---------------------------------------------------------------------------
// SimpleTernaryNet forward, MFMA-f16 for conv1 + conv2 + fc1.
//   tern(w) -> conv3x3(3->16)+b+relu -> maxpool2      (f16 MFMA 16x16x32, 2/pos)
//           -> conv3x3(16->32)+b+relu -> maxpool2     (f16 MFMA 16x16x32, tap-pairs)
//           -> fc(2048->128)+b+relu                   (f16 MFMA, K-split 16 waves)
//           -> fc(128->10)+b                          (fp32 VALU)
//
// Round-11: conv1/conv2 moved from legacy 16x16x16 to native gfx950 16x16x32
// (conv2: 9 taps -> 5 K=32 MFMAs via tap pairing; conv1: 3 K=16 -> 2 K=32).
// MFMA instr/wave 120 -> 72. Weights pre-packed in K=32 fragment order.
//
// ws layout (bytes):
//   [0)         tw1f   f16 [2][64][8] conv1 B-frags   2048 B
//   [2048)      tw2f   f16 [5][2][64][8] conv2 B-frags 10240 B
//   [12288)     twf1   f16 [128 n][2048 k]            524288 B
//   [536576)    twf2   f32 [10][128]                  5120 B
//   [541696)    h2p    f16 [4096][2048]               16777216 B
//   [17318912)  partials f32 sum[64], sa[64], cnt[64]
// ---------------------------------------------------------------------------

typedef _Float16 half2v __attribute__((ext_vector_type(2)));
typedef _Float16 half4  __attribute__((ext_vector_type(4)));
typedef _Float16 half8  __attribute__((ext_vector_type(8)));
typedef float    f32x4  __attribute__((ext_vector_type(4)));
typedef unsigned u32x2  __attribute__((ext_vector_type(2)));
typedef unsigned u32x4  __attribute__((ext_vector_type(4)));

#define WF1_N 262144
#define WF1_SLICES 64
#define WF1_SLICE 4096

__device__ __forceinline__ float block_reduce_256(float v, float* red, int t) {
    red[t] = v; __syncthreads();
    for (int o = 128; o > 0; o >>= 1) {
        if (t < o) red[t] += red[t + o];
        __syncthreads();
    }
    float r = red[0]; __syncthreads();
    return r;
}

__device__ __forceinline__ unsigned pk16(float a, float b) {
    half2v h;
    h[0] = (_Float16)a;
    h[1] = (_Float16)b;
    return __builtin_bit_cast(unsigned, h);
}

// ---------------- stage A: wf1 partial |sum| + small tensors complete ------
__global__ void tern_stageA(const float* __restrict__ w1,
                            const float* __restrict__ w2,
                            const float* __restrict__ wf1,
                            const float* __restrict__ wf2,
                            _Float16* __restrict__ tw1f,
                            _Float16* __restrict__ tw2f,
                            float* __restrict__ twf2,
                            float* __restrict__ part_sum) {
    __shared__ float red[256];
    const int t = threadIdx.x;
    const int bid = blockIdx.x;

    if (bid < WF1_SLICES) {
        const float4* src = reinterpret_cast<const float4*>(wf1 + (size_t)bid * WF1_SLICE);
        float s = 0.f;
#pragma unroll
        for (int j = 0; j < 4; ++j) {
            const float4 v = src[t + j * 256];
            s += fabsf(v.x) + fabsf(v.y) + fabsf(v.z) + fabsf(v.w);
        }
        const float tot = block_reduce_256(s, red, t);
        if (t == 0) part_sum[bid] = tot;
        return;
    }

    const float* w;
    int n;
    const int which = bid - WF1_SLICES;  // 0:w1 1:w2 2:wf2
    switch (which) {
        case 0: w = w1;  n = 432;  break;
        case 1: w = w2;  n = 4608; break;
        default: w = wf2; n = 1280; break;
    }
    float s = 0.f;
    for (int i = t; i < n; i += 256) s += fabsf(w[i]);
    const float delta = 0.7f * block_reduce_256(s, red, t) / (float)n;
    float sa = 0.f, cnt = 0.f;
    for (int i = t; i < n; i += 256) {
        float a = fabsf(w[i]);
        if (a > delta) { sa += a; cnt += 1.f; }
    }
    const float tot_sa = block_reduce_256(sa, red, t);
    const float tot_cnt = block_reduce_256(cnt, red, t);
    const float alpha = tot_sa / fmaxf(tot_cnt, 1.0f);

    switch (which) {
        case 0:
            // conv1 B-frags, K=32 (2 MFMAs): entry o=(m*64+l)*8+j.
            // k=g8*8+j (g8=l>>4); rho=m*8+g8*2+(j>>2); tap=j&3; co=l&15.
            // value = w1[co][c=rho/3][ky=rho%3][kx=tap], 0 if rho>8 or tap==3.
            for (int o = t; o < 1024; o += 256) {
                int j = o & 7;
                int l = (o >> 3) & 63;
                int m = o >> 9;
                int g8 = l >> 4;
                int rho = m * 8 + g8 * 2 + (j >> 2);
                int tap = j & 3;
                int co = l & 15;
                float v = 0.f;
                if (rho < 9 && tap < 3) {
                    float wv = w1[co * 27 + (rho / 3) * 9 + (rho % 3) * 3 + tap];
                    v = (fabsf(wv) > delta) ? copysignf(alpha, wv) : 0.f;
                }
                tw1f[o] = (_Float16)v;
            }
            break;
        case 1:
            // conv2 B-frags, K=32 tap-pairs (5 MFMAs): entry o=((p*2+nt)*64+l)*8+j.
            // k=g8*8+j; tap t=p*2+(k>>4); ci=k&15; co=(l&15)+nt*16; 0 if t>8.
            for (int o = t; o < 5120; o += 256) {
                int j  = o & 7;
                int l  = (o >> 3) & 63;
                int nt = (o >> 9) & 1;
                int pp = o >> 10;
                int g8 = l >> 4;
                int k  = g8 * 8 + j;
                int tt = pp * 2 + (k >> 4);
                int ci = k & 15;
                int co = (l & 15) + nt * 16;
                float v = 0.f;
                if (tt < 9) {
                    float wv = w2[(co * 16 + ci) * 9 + tt];
                    v = (fabsf(wv) > delta) ? copysignf(alpha, wv) : 0.f;
                }
                tw2f[o] = (_Float16)v;
            }
            break;
        default:
            for (int o = t; o < 1280; o += 256) {
                float wv = wf2[o];
                twf2[o] = (fabsf(wv) > delta) ? copysignf(alpha, wv) : 0.f;
            }
            break;
    }
}

// ---------------- stage B: delta (redundant) + masked partials -------------
__global__ void tern_stageB(const float* __restrict__ wf1,
                            const float* __restrict__ part_sum,
                            float* __restrict__ part_sa,
                            float* __restrict__ part_cnt) {
    __shared__ float red[256];
    const int t = threadIdx.x;
    const int bid = blockIdx.x;

    float v = (t < WF1_SLICES) ? part_sum[t] : 0.f;
    const float delta = 0.7f * block_reduce_256(v, red, t) / (float)WF1_N;

    const float4* src = reinterpret_cast<const float4*>(wf1 + (size_t)bid * WF1_SLICE);
    float sa = 0.f, cnt = 0.f;
#pragma unroll
    for (int j = 0; j < 4; ++j) {
        const float4 w4 = src[t + j * 256];
        float a;
        a = fabsf(w4.x); if (a > delta) { sa += a; cnt += 1.f; }
        a = fabsf(w4.y); if (a > delta) { sa += a; cnt += 1.f; }
        a = fabsf(w4.z); if (a > delta) { sa += a; cnt += 1.f; }
        a = fabsf(w4.w); if (a > delta) { sa += a; cnt += 1.f; }
    }
    const float tot_sa = block_reduce_256(sa, red, t);
    const float tot_cnt = block_reduce_256(cnt, red, t);
    if (t == 0) { part_sa[bid] = tot_sa; part_cnt[bid] = tot_cnt; }
}

// ---------------- stage C: alpha (redundant) + f16 ternary write -----------
__global__ void tern_stageC(const float* __restrict__ wf1,
                            const float* __restrict__ part_sum,
                            const float* __restrict__ part_sa,
                            const float* __restrict__ part_cnt,
                            _Float16* __restrict__ twf1) {
    __shared__ float red[256];
    const int t = threadIdx.x;

    float v = (t < WF1_SLICES) ? part_sum[t] : 0.f;
    const float delta = 0.7f * block_reduce_256(v, red, t) / (float)WF1_N;
    v = (t < WF1_SLICES) ? part_sa[t] : 0.f;
    const float tot_sa = block_reduce_256(v, red, t);
    v = (t < WF1_SLICES) ? part_cnt[t] : 0.f;
    const float tot_cnt = block_reduce_256(v, red, t);
    const float alpha = tot_sa / fmaxf(tot_cnt, 1.0f);

    const int tid = blockIdx.x * 256 + t;  // 65536 threads x 4 elems
    const float4 w4 = reinterpret_cast<const float4*>(wf1)[tid];
    half4 hv;
    hv[0] = (_Float16)((fabsf(w4.x) > delta) ? copysignf(alpha, w4.x) : 0.f);
    hv[1] = (_Float16)((fabsf(w4.y) > delta) ? copysignf(alpha, w4.y) : 0.f);
    hv[2] = (_Float16)((fabsf(w4.z) > delta) ? copysignf(alpha, w4.z) : 0.f);
    hv[3] = (_Float16)((fabsf(w4.w) > delta) ? copysignf(alpha, w4.w) : 0.f);
    reinterpret_cast<half4*>(twf1)[tid] = hv;
}

// ---------------- fused conv1(MFMA)+pool + conv2(MFMA)+pool ----------------
// H1P=18: pixel stride 9 dwords (odd) -> conv2 A-read bank conflicts 2-way (free).
#define H1P 18
#define PSZ 3472          // 3*34*34=3468 + 4 pad f16 (6944 B, /16 ok)
#define H1SZ (18*18*H1P)  // 5832 f16 = 11664 B (/16 ok)

__global__ __launch_bounds__(256, 5)
void conv12_kernel(const float* __restrict__ x,      // [B,3,32,32]
                   const float* __restrict__ b1,     // [16]
                   const float* __restrict__ b2,     // [32]
                   const _Float16* __restrict__ tw1f,// [2][64][8] f16 B-frags
                   const _Float16* __restrict__ tw2f,// [5][2][64][8] f16 B-frags
                   _Float16* __restrict__ h2p) {     // [B,2048] f16
    __shared__ __align__(16) _Float16 PA[PSZ];          // planar f16 [3][34][34]
    __shared__ __align__(16) _Float16 PB[PSZ];          // PB[i] = PA[i+1]
    __shared__ __align__(16) _Float16 h1s[H1SZ];        // (y*18+x)*18 + ci
    __shared__ __align__(16) _Float16 h2s[2048];        // co*64 + py*8 + px
    __shared__ float b1s[16], b2s[32];

    const int t = threadIdx.x;
    const int b = blockIdx.x;
    const int wid = t >> 6, l = t & 63;

    // issue x loads FIRST (3x float4, coalesced) so HBM latency hides
    // under the zero phase
    float4 xv4[3];
    {
        const float4* xb4 = reinterpret_cast<const float4*>(x + (size_t)b * 3072);
#pragma unroll
        for (int j = 0; j < 3; ++j) xv4[j] = xb4[t + j * 256];
    }
    // conv1 B-frags (L2-resident), K=32 order
    half8 w1f[2];
#pragma unroll
    for (int m = 0; m < 2; ++m)
        w1f[m] = *reinterpret_cast<const half8*>(tw1f + (size_t)(m * 64 + l) * 8);
    if (t < 16) b1s[t] = b1[t];
    if (t < 32) b2s[t] = b2[t];

    // zero LDS via float4 (halos / garbage-tap safety)
    {
        const float4 z = {0.f, 0.f, 0.f, 0.f};
        float4* pa4 = reinterpret_cast<float4*>(PA);
        float4* pb4 = reinterpret_cast<float4*>(PB);
        float4* h14 = reinterpret_cast<float4*>(h1s);
        for (int i = t; i < PSZ * 2 / 16; i += 256) { pa4[i] = z; pb4[i] = z; }
        for (int i = t; i < H1SZ * 2 / 16; i += 256) h14[i] = z;
    }
    __syncthreads();

    // phase 1: stage x -> planar f16 PA + shifted copy PB (parity-aware u32)
    {
#pragma unroll
        for (int j = 0; j < 3; ++j) {
            const int f = t + j * 256;           // float4 group id, 768 total
            const int c = f >> 8, rem = f & 255;
            const int iy = rem >> 3, ix = (rem & 7) << 2;
            const int idx = ((c * 34) + iy + 1) * 34 + 1 + ix;
            const float4 v = xv4[j];
            const unsigned w0 = __builtin_bit_cast(unsigned, __builtin_amdgcn_cvt_pkrtz(v.x, v.y));
            const unsigned w1 = __builtin_bit_cast(unsigned, __builtin_amdgcn_cvt_pkrtz(v.z, v.w));
            const half2v h0 = __builtin_bit_cast(half2v, w0);
            const half2v h1 = __builtin_bit_cast(half2v, w1);
            *reinterpret_cast<unsigned*>(&PB[idx - 1]) = w0;
            *reinterpret_cast<unsigned*>(&PB[idx + 1]) = w1;
            PA[idx] = h0[0];
            *reinterpret_cast<unsigned*>(&PA[idx + 1]) = (w0 >> 16) | (w1 << 16);
            PA[idx + 3] = h1[1];
        }
    }
    __syncthreads();

    // phase 2: conv1 via 2x chained 16x16x32 MFMA.
    // MFMA m, lane g8 covers rhos {m*8+2g8, m*8+2g8+1} x taps 0..3.
    // Only rho<=8 real (B zero elsewhere); dead rhos read rho 0 (finite).
    {
        const int r15 = l & 15, g8 = l >> 4;
        const int p = r15 & 1;
        int li[4];
        {
            const int rhos[4] = {2 * g8, 2 * g8 + 1, (g8 == 0) ? 8 : 0, 0};
#pragma unroll
            for (int r = 0; r < 4; ++r) {
                const int c = rhos[r] / 3, ky = rhos[r] % 3;
                li[r] = ((c * 34 + ky) * 34 + r15 - p) >> 1;
            }
        }
        const unsigned* basep = p ? reinterpret_cast<const unsigned*>(PB)
                                  : reinterpret_cast<const unsigned*>(PA);
        const float bia = b1s[r15];

#pragma unroll 1
        for (int i = 0; i < 8; ++i) {
            const int P = wid * 8 + i;
            const int py = P >> 1, xh = P & 1;
            const int x0 = xh * 16;
            f32x4 accA = {0.f, 0.f, 0.f, 0.f};
            f32x4 accB = {0.f, 0.f, 0.f, 0.f};
#pragma unroll
            for (int h2 = 0; h2 < 2; ++h2) {
                const int y = 2 * py + h2;
                const int uoff = (y * 34 + x0) >> 1;
                f32x4 acc = {0.f, 0.f, 0.f, 0.f};
                u32x4 d;
                d.x = basep[li[0] + uoff]; d.y = basep[li[0] + uoff + 1];
                d.z = basep[li[1] + uoff]; d.w = basep[li[1] + uoff + 1];
                acc = __builtin_amdgcn_mfma_f32_16x16x32_f16(
                    __builtin_bit_cast(half8, d), w1f[0], acc, 0, 0, 0);
                d.x = basep[li[2] + uoff]; d.y = basep[li[2] + uoff + 1];
                d.z = basep[li[3] + uoff]; d.w = basep[li[3] + uoff + 1];
                acc = __builtin_amdgcn_mfma_f32_16x16x32_f16(
                    __builtin_bit_cast(half8, d), w1f[1], acc, 0, 0, 0);
                if (h2 == 0) accA = acc; else accB = acc;
            }
            // 2x2 maxpool on regs (x = g8*4 + reg), then bias+relu
            float e0 = fmaxf(fmaxf(accA[0], accA[1]), fmaxf(accB[0], accB[1]));
            float e1 = fmaxf(fmaxf(accA[2], accA[3]), fmaxf(accB[2], accB[3]));
            e0 = fmaxf(e0 + bia, 0.f);
            e1 = fmaxf(e1 + bia, 0.f);
            const int px0 = xh * 8 + g8 * 2;
            const int pix = (py + 1) * 18 + (px0 + 1);
            h1s[pix * H1P + r15]       = (_Float16)e0;
            h1s[(pix + 1) * H1P + r15] = (_Float16)e1;
        }
    }

    // conv2 B-frags (global, per-lane 16B, coalesced, L2-resident)
    half8 bfr2[5][2];
#pragma unroll
    for (int pp = 0; pp < 5; ++pp)
#pragma unroll
        for (int nt = 0; nt < 2; ++nt)
            bfr2[pp][nt] = *reinterpret_cast<const half8*>(
                tw2f + (size_t)((pp * 2 + nt) * 64 + l) * 8);
    __syncthreads();

    // phase 3: conv2 via 5x 16x16x32 MFMA (tap pairs) + bias + relu + pool.
    // Lane g8: pair member tp=g8>>1, ci-half (g8&1)*8. Per-lane tap offsets
    // are yy-invariant -> precompute offp[5].
    {
        const int xq = l & 15, g8 = l >> 4;
        const int tp = g8 >> 1, lo8 = (g8 & 1) * 4;  // dword offset within pixel
        int offp[5];
#pragma unroll
        for (int pp = 0; pp < 5; ++pp) {
            const int ta = 2 * pp;
            const int tb = (2 * pp + 1 > 8) ? 8 : 2 * pp + 1;
            const int tt = tp ? tb : ta;
            offp[pp] = ((tt / 3) * 18 + (tt % 3)) * 9 + lo8;
        }
        const unsigned* h1u = reinterpret_cast<const unsigned*>(h1s);
        float sav[2][2];
#pragma unroll
        for (int yy = 0; yy < 4; ++yy) {
            const int y = wid * 4 + yy;
            const int base = (y * 18 + xq) * 9;
            f32x4 acc0 = {0.f, 0.f, 0.f, 0.f};
            f32x4 acc1 = {0.f, 0.f, 0.f, 0.f};
#pragma unroll
            for (int pp = 0; pp < 5; ++pp) {
                const unsigned* q = h1u + base + offp[pp];
                u32x4 d;
                d.x = q[0]; d.y = q[1]; d.z = q[2]; d.w = q[3];
                const half8 a = __builtin_bit_cast(half8, d);
                acc0 = __builtin_amdgcn_mfma_f32_16x16x32_f16(a, bfr2[pp][0], acc0, 0, 0, 0);
                acc1 = __builtin_amdgcn_mfma_f32_16x16x32_f16(a, bfr2[pp][1], acc1, 0, 0, 0);
            }
            // x-pool: lane regs are pixels x = g8*4 + r
            const float p00 = fmaxf(acc0[0], acc0[1]);
            const float p01 = fmaxf(acc0[2], acc0[3]);
            const float p10 = fmaxf(acc1[0], acc1[1]);
            const float p11 = fmaxf(acc1[2], acc1[3]);
            if ((yy & 1) == 0) {
                sav[0][0] = p00; sav[0][1] = p01;
                sav[1][0] = p10; sav[1][1] = p11;
            } else {
                const int py = (wid * 4 + yy) >> 1;
                const float v00 = fmaxf(fmaxf(sav[0][0], p00) + b2s[xq], 0.f);
                const float v01 = fmaxf(fmaxf(sav[0][1], p01) + b2s[xq], 0.f);
                const float v10 = fmaxf(fmaxf(sav[1][0], p10) + b2s[xq + 16], 0.f);
                const float v11 = fmaxf(fmaxf(sav[1][1], p11) + b2s[xq + 16], 0.f);
                unsigned* h2u = reinterpret_cast<unsigned*>(h2s);
                h2u[xq * 32 + py * 4 + g8]        = pk16(v00, v01);
                h2u[(xq + 16) * 32 + py * 4 + g8] = pk16(v10, v11);
            }
        }
    }
    __syncthreads();

    // phase 4: h2s -> global (coalesced 16B/thread)
    {
        const float4 v = reinterpret_cast<const float4*>(h2s)[t];
        reinterpret_cast<float4*>(h2p + (size_t)b * 2048)[t] = v;
    }
}

// ---------------- fc1 (MFMA f16, K-split over 16 waves) + fc2 fused --------
__global__ __launch_bounds__(1024, 4)
void fc_kernel(const _Float16* __restrict__ h2p,   // [B,2048]
               const _Float16* __restrict__ twf1,  // [128 n][2048 k]
               const float* __restrict__ bf1,      // [128]
               const float* __restrict__ twf2,     // [10][128]
               const float* __restrict__ bf2,      // [10]
               float* __restrict__ out) {          // [B,10]
    __shared__ float red[8][2048];                 // 64 KB reduction buffer

    const int t = threadIdx.x;
    const int wid = t >> 6, l = t & 63;
    const int lx = l & 15, g = l >> 4;
    const int m0 = blockIdx.x * 16;

    f32x4 acc[8];
#pragma unroll
    for (int nt = 0; nt < 8; ++nt) acc[nt] = (f32x4){0.f, 0.f, 0.f, 0.f};

    const int kb = wid * 128;
#pragma unroll
    for (int it = 0; it < 4; ++it) {
        const int k0 = kb + it * 32;
        const half8 a = *reinterpret_cast<const half8*>(
            h2p + (size_t)(m0 + lx) * 2048 + k0 + g * 8);
#pragma unroll
        for (int nt = 0; nt < 8; ++nt) {
            const half8 bb = *reinterpret_cast<const half8*>(
                twf1 + (size_t)(nt * 16 + lx) * 2048 + k0 + g * 8);
            acc[nt] = __builtin_amdgcn_mfma_f32_16x16x32_f16(a, bb, acc[nt], 0, 0, 0);
        }
    }

    // tree-reduce 16 wave partials -> wave 0
    for (int h = 8; h >= 1; h >>= 1) {
        if (wid >= h && wid < 2 * h) {
            float* dst = &red[wid - h][0];
#pragma unroll
            for (int nt = 0; nt < 8; ++nt)
                *reinterpret_cast<f32x4*>(dst + nt * 256 + l * 4) = acc[nt];
        }
        __syncthreads();
        if (wid < h) {
            const float* srcp = &red[wid][0];
#pragma unroll
            for (int nt = 0; nt < 8; ++nt) {
                const f32x4 v = *reinterpret_cast<const f32x4*>(srcp + nt * 256 + l * 4);
                acc[nt] += v;
            }
        }
        __syncthreads();
    }

    // wave 0: bias + relu -> Hs (stored in red[0])
    if (wid == 0) {
#pragma unroll
        for (int nt = 0; nt < 8; ++nt) {
            const int col = nt * 16 + lx;
            const float bias = bf1[col];
#pragma unroll
            for (int r = 0; r < 4; ++r)
                red[0][(g * 4 + r) * 128 + col] = fmaxf(acc[nt][r] + bias, 0.f);
        }
    }
    __syncthreads();

    // fc2: 160 outputs (16 rows x 10)
    if (t < 160) {
        const int m = t / 10, n = t % 10;
        float a = bf2[n];
#pragma unroll 8
        for (int k = 0; k < 128; ++k) a += red[0][m * 128 + k] * twf2[n * 128 + k];
        out[(size_t)(m0 + m) * 10 + n] = a;
    }
}

// ---------------------------------------------------------------------------
extern "C" void kernel_launch(void* const* d_in, const int* in_sizes, int n_in,
                              void* d_out, int out_size, void* d_ws, size_t ws_size,
                              hipStream_t stream) {
    const float* x   = (const float*)d_in[0];
    const float* w1  = (const float*)d_in[1];
    const float* b1  = (const float*)d_in[2];
    const float* w2  = (const float*)d_in[3];
    const float* b2  = (const float*)d_in[4];
    const float* wf1 = (const float*)d_in[5];
    const float* bf1 = (const float*)d_in[6];
    const float* wf2 = (const float*)d_in[7];
    const float* bf2 = (const float*)d_in[8];
    float* out = (float*)d_out;
    const int B = in_sizes[0] / (3 * 32 * 32);  // 4096

    char* ws = (char*)d_ws;
    _Float16*  tw1f  = (_Float16*)(ws + 0);
    _Float16*  tw2f  = (_Float16*)(ws + 2048);
    _Float16*  twf1  = (_Float16*)(ws + 12288);
    float*     twf2  = (float*)(ws + 536576);
    _Float16*  h2p   = (_Float16*)(ws + 541696);
    float*     part_sum = (float*)(ws + 17318912);
    float*     part_sa  = part_sum + 64;
    float*     part_cnt = part_sa + 64;

    tern_stageA<<<WF1_SLICES + 3, 256, 0, stream>>>(w1, w2, wf1, wf2,
                                                    tw1f, tw2f, twf2, part_sum);
    tern_stageB<<<WF1_SLICES, 256, 0, stream>>>(wf1, part_sum, part_sa, part_cnt);
    tern_stageC<<<256, 256, 0, stream>>>(wf1, part_sum, part_sa, part_cnt, twf1);
    conv12_kernel<<<B, 256, 0, stream>>>(x, b1, b2, tw1f, tw2f, h2p);
    fc_kernel<<<B / 16, 1024, 0, stream>>>(h2p, twf1, bf1, twf2, bf2, out);
}